// Round 7
// baseline (3802.550 us; speedup 1.0000x reference)
//
#include <hip/hip_runtime.h>

#define R_ET 8
#define DH 128
#define KST 1152  // stacked K: 8 relation blocks + root block
#define GS 1028   // LDS G row stride in dwords (1024 + 4 pad for bank spread)

typedef __bf16 bf16x8 __attribute__((ext_vector_type(8)));
typedef float f32x4 __attribute__((ext_vector_type(4)));

__device__ __forceinline__ ushort f2bf(float f) {
  unsigned u = __float_as_uint(f);
  u += 0x7fff + ((u >> 16) & 1);  // round-to-nearest-even
  return (ushort)(u >> 16);
}

// Swizzled bf16 activation layout: element (row, k) at row*128 + ((k>>3)^(row&7))*8 + (k&7).
// r3 lesson: global-atomic cost ~ RMWs-per-line; keep counters spread.
// r5 lesson: 391 blocks = TLP collapse.
// r6 lesson: per-(dst,r) segment loops are overhead-bound at avg 2 edges/segment ->
// this version streams the tile's WHOLE edge run edge-parallel into fp32 LDS via
// ds_add_f32 (no return -> no stall, no segmentation, full unroll).

// ---------------- degree count per (dst, etype) segment ----------------
__global__ void count_kernel(const int* __restrict__ ei, const int* __restrict__ et,
                             int* __restrict__ cnt, int E) {
  int e = blockIdx.x * blockDim.x + threadIdx.x;
  if (e < E) atomicAdd(&cnt[ei[E + e] * R_ET + et[e]], 1);
}

// ---------------- 3-phase exclusive scan over M = N*R segment counts ----------------
__global__ __launch_bounds__(1024) void scanA(const int* __restrict__ cnt,
                                              int* __restrict__ off,
                                              int* __restrict__ bsum, int M) {
  __shared__ int s[1024];
  int tid = threadIdx.x;
  int i = blockIdx.x * 1024 + tid;
  int d = (i < M) ? cnt[i] : 0;
  s[tid] = d;
  __syncthreads();
  for (int st = 1; st < 1024; st <<= 1) {
    int v = (tid >= st) ? s[tid - st] : 0;
    __syncthreads();
    s[tid] += v;
    __syncthreads();
  }
  if (i < M) off[i] = s[tid] - d;
  if (tid == 1023) bsum[blockIdx.x] = s[1023];
}

__global__ __launch_bounds__(1024) void scanB(int* __restrict__ bsum, int nb) {
  __shared__ int s[1024];
  int tid = threadIdx.x;
  int v = (tid < nb) ? bsum[tid] : 0;
  s[tid] = v;
  __syncthreads();
  for (int st = 1; st < 1024; st <<= 1) {
    int x = (tid >= st) ? s[tid - st] : 0;
    __syncthreads();
    s[tid] += x;
    __syncthreads();
  }
  if (tid < nb) bsum[tid] = s[tid] - v;
}

__global__ __launch_bounds__(1024) void scanC(int* __restrict__ off,
                                              int* __restrict__ cursor,
                                              const int* __restrict__ bsum,
                                              int M, int E) {
  int i = blockIdx.x * 1024 + threadIdx.x;
  if (i < M) {
    int o = off[i] + bsum[blockIdx.x];
    off[i] = o;
    cursor[i] = o;
  }
  if (i == 0) off[M] = E;
}

// ---------------- place edges into (dst, r)-sorted slots ----------------
// meta: x = src | (dst&15)<<16 | r<<20 (requires N <= 65536), y = 1/cnt(dst,r)
__global__ void place_kernel(const int* __restrict__ ei, const int* __restrict__ et,
                             const int* __restrict__ cnt, int* __restrict__ cursor,
                             int2* __restrict__ meta, int E) {
  int e = blockIdx.x * blockDim.x + threadIdx.x;
  if (e >= E) return;
  int src = ei[e], dst = ei[E + e], r = et[e];
  int seg = dst * R_ET + r;
  int slot = atomicAdd(&cursor[seg], 1);
  meta[slot] = make_int2(src | ((dst & 15) << 16) | (r << 20),
                         __float_as_int(1.f / (float)cnt[seg]));
}

// ------- stacked weight convert: Wt[n][k], k = r*128+kin (r<8) or 1024+kin (root) ----
__global__ __launch_bounds__(256) void wconv_kernel(const float* __restrict__ root,
                                                    const float* __restrict__ W,
                                                    ushort* __restrict__ Wt) {
  int mat = blockIdx.x;  // 0..7 = W[r], 8 = root
  const float* src = (mat == 8) ? root : (W + (size_t)mat * DH * DH);
  for (int idx = threadIdx.x; idx < DH * DH; idx += 256) {
    int n = idx >> 7, kin = idx & 127;
    int k = mat * DH + kin;
    Wt[(size_t)n * KST + (((k >> 3) ^ (n & 7)) << 3) + (k & 7)] = f2bf(src[kin * DH + n]);
  }
}

// ---------------- activation convert (layer 0), zero-pads rows, swizzled ----------------
__global__ __launch_bounds__(256) void aconv_kernel(const float* __restrict__ src,
                                                    ushort* __restrict__ dst,
                                                    int total, int padtotal) {
  int i4 = (blockIdx.x * 256 + threadIdx.x) * 4;
  if (i4 >= padtotal) return;
  int row = i4 >> 7, k = i4 & 127;
  ushort4 o = make_ushort4(0, 0, 0, 0);
  if (i4 < total) {
    float4 v = *(const float4*)&src[i4];
    o = make_ushort4(f2bf(v.x), f2bf(v.y), f2bf(v.z), f2bf(v.w));
  }
  *(ushort4*)&dst[(size_t)row * DH + (((k >> 3) ^ (row & 7)) << 3) + (k & 7)] = o;
}

// ============ fused RGCN layer: edge-parallel LDS-atomic agg + K=1152 GEMM ==========
// Block = 16 dsts, 512 threads (8 waves). Phase 1: all waves stream the tile's
// contiguous (dst,r)-sorted edge run in 32-edge chunks; per edge, lanes cover
// features (lane, 64+lane): 2 ushort loads from Ain (L3-resident) + 2 ds_add_f32
// into G[dstLocal][r*128+feat]. Phase 2: GEMM [16 x 1152] x [1152 x 128]; wave =
// (col-half ng, K-quarter kgrp); af read once per kstep feeds 4 n-frag MFMAs;
// root K-block [1024,1152) read straight from Ain (global). Phase 3/4: K-partials
// exchanged through the (now free) G region. mfma(bw, af): D.l15 = dst, D.(quad,
// reg) = col.
__global__ __launch_bounds__(512, 4) void rgcn_layer(
    const ushort* __restrict__ Ain, const int* __restrict__ off2,
    const int2* __restrict__ meta, const ushort* __restrict__ Wt,
    const float* __restrict__ bias, ushort* __restrict__ Aout,
    float* __restrict__ pbuf, int N, int last) {
  __shared__ __align__(16) float G[16 * GS];  // 64.25 KB -> 2 blocks/CU
  const int tid = threadIdx.x;
  const int wave = tid >> 6, lane = tid & 63;
  const int quad = lane >> 4, l15 = lane & 15;
  const int rbase = blockIdx.x * 16;

  // ---- phase 0: zero the relation region (16 rows x 1024 dwords) ----
#pragma unroll
  for (int it = 0; it < 8; it++) {
    int i4 = it * 512 + tid;
    int row = i4 >> 8, kd = (i4 & 255) * 4;
    *(f32x4*)&G[row * GS + kd] = (f32x4){0.f, 0.f, 0.f, 0.f};
  }
  __syncthreads();

  // ---- phase 1: edge-parallel aggregation ----
  {
    const int kb = lane >> 3, klo = lane & 7;  // features k=lane and k=64+lane
    const int rend = min(rbase + 16, N);
    const int start = off2[rbase * R_ET];
    const int end = off2[rend * R_ET];
    for (int base = start + wave * 32; base < end; base += 256) {
      int m = min(32, end - base);
      int2 md = make_int2(0, 0);
      if (lane < m) md = meta[base + lane];
      int j = 0;
      for (; j + 4 <= m; j += 4) {
        int p0 = __shfl(md.x, j),     p1 = __shfl(md.x, j + 1);
        int p2 = __shfl(md.x, j + 2), p3 = __shfl(md.x, j + 3);
        float c0 = __int_as_float(__shfl(md.y, j));
        float c1 = __int_as_float(__shfl(md.y, j + 1));
        float c2 = __int_as_float(__shfl(md.y, j + 2));
        float c3 = __int_as_float(__shfl(md.y, j + 3));
        const ushort* q0 = Ain + (((size_t)(p0 & 0xffff)) << 7) + ((kb ^ (p0 & 7)) << 3) + klo;
        const ushort* q1 = Ain + (((size_t)(p1 & 0xffff)) << 7) + ((kb ^ (p1 & 7)) << 3) + klo;
        const ushort* q2 = Ain + (((size_t)(p2 & 0xffff)) << 7) + ((kb ^ (p2 & 7)) << 3) + klo;
        const ushort* q3 = Ain + (((size_t)(p3 & 0xffff)) << 7) + ((kb ^ (p3 & 7)) << 3) + klo;
        unsigned a0 = q0[0], b0 = q0[64];
        unsigned a1 = q1[0], b1 = q1[64];
        unsigned a2 = q2[0], b2 = q2[64];
        unsigned a3 = q3[0], b3 = q3[64];
        int g0 = ((p0 >> 16) & 15) * GS + ((p0 >> 20) & 7) * 128 + lane;
        int g1 = ((p1 >> 16) & 15) * GS + ((p1 >> 20) & 7) * 128 + lane;
        int g2 = ((p2 >> 16) & 15) * GS + ((p2 >> 20) & 7) * 128 + lane;
        int g3 = ((p3 >> 16) & 15) * GS + ((p3 >> 20) & 7) * 128 + lane;
        atomicAdd(&G[g0], __uint_as_float(a0 << 16) * c0);
        atomicAdd(&G[g0 + 64], __uint_as_float(b0 << 16) * c0);
        atomicAdd(&G[g1], __uint_as_float(a1 << 16) * c1);
        atomicAdd(&G[g1 + 64], __uint_as_float(b1 << 16) * c1);
        atomicAdd(&G[g2], __uint_as_float(a2 << 16) * c2);
        atomicAdd(&G[g2 + 64], __uint_as_float(b2 << 16) * c2);
        atomicAdd(&G[g3], __uint_as_float(a3 << 16) * c3);
        atomicAdd(&G[g3 + 64], __uint_as_float(b3 << 16) * c3);
      }
      for (; j < m; j++) {
        int p = __shfl(md.x, j);
        float c = __int_as_float(__shfl(md.y, j));
        const ushort* q = Ain + (((size_t)(p & 0xffff)) << 7) + ((kb ^ (p & 7)) << 3) + klo;
        unsigned a = q[0], b = q[64];
        int g = ((p >> 16) & 15) * GS + ((p >> 20) & 7) * 128 + lane;
        atomicAdd(&G[g], __uint_as_float(a << 16) * c);
        atomicAdd(&G[g + 64], __uint_as_float(b << 16) * c);
      }
    }
  }
  __syncthreads();

  // ---- phase 2: GEMM partials. wave = (ng = col half, kgrp = K quarter) ----
  const int ng = wave & 1, kgrp = wave >> 1;
  const int swz = l15 & 7;  // = n&7 = node&7 (rbase, col bases are multiples of 16)
  const ushort* Wb = Wt + (size_t)(ng * 64 + l15) * KST;
  const ushort* Arow = Ain + ((size_t)(rbase + l15) << 7);
  f32x4 acc[4];
#pragma unroll
  for (int j = 0; j < 4; j++) acc[j] = (f32x4){0.f, 0.f, 0.f, 0.f};
#pragma unroll
  for (int s = 0; s < 9; s++) {
    const int t = kgrp * 9 + s;
    const int b8 = t * 4 + quad;  // 16B k-block index, 0..143
    bf16x8 af;
    if (t < 32) {  // relation blocks from LDS fp32 (plain layout)
      const float* gp = &G[l15 * GS + b8 * 8];
      f32x4 a0 = *(const f32x4*)gp;
      f32x4 a1 = *(const f32x4*)(gp + 4);
      af[0] = (__bf16)a0[0]; af[1] = (__bf16)a0[1];
      af[2] = (__bf16)a0[2]; af[3] = (__bf16)a0[3];
      af[4] = (__bf16)a1[0]; af[5] = (__bf16)a1[1];
      af[6] = (__bf16)a1[2]; af[7] = (__bf16)a1[3];
    } else {       // root block straight from Ain (bf16, swizzled row)
      af = *(const bf16x8*)&Arow[((b8 - 128) ^ swz) << 3];
    }
#pragma unroll
    for (int j = 0; j < 4; j++) {
      bf16x8 bw = *(const bf16x8*)&Wb[j * 16 * KST + ((b8 ^ swz) << 3)];
      acc[j] = __builtin_amdgcn_mfma_f32_16x16x32_bf16(bw, af, acc[j], 0, 0, 0);
    }
  }
  __syncthreads();  // all G reads done; region becomes partial-exchange scratch

  // ---- phase 3: write K-partials ----
  float* P = G;
#pragma unroll
  for (int j = 0; j < 4; j++)
    *(f32x4*)&P[wave * 1024 + j * 256 + lane * 4] = acc[j];
  __syncthreads();

  // ---- phase 4: wave f reduces n-frag f over the 4 K-quarters ----
  const int fng = wave >> 2, fj = wave & 3;
  f32x4 rr = (f32x4){0.f, 0.f, 0.f, 0.f};
#pragma unroll
  for (int k = 0; k < 4; k++) {
    f32x4 p = *(const f32x4*)&P[(fng + 2 * k) * 1024 + fj * 256 + lane * 4];
#pragma unroll
    for (int c = 0; c < 4; c++) rr[c] += p[c];
  }

  // ---- phase 5: epilogue ----
  const int node = rbase + l15;
  const int c0 = fng * 64 + fj * 16 + quad * 4;
  if (!last) {
    if (node < N) {
      float4 bv = *(const float4*)&bias[c0];
      unsigned lo = (unsigned)f2bf(fmaxf(rr[0] + bv.x, 0.f)) |
                    ((unsigned)f2bf(fmaxf(rr[1] + bv.y, 0.f)) << 16);
      unsigned hi = (unsigned)f2bf(fmaxf(rr[2] + bv.z, 0.f)) |
                    ((unsigned)f2bf(fmaxf(rr[3] + bv.w, 0.f)) << 16);
      *(uint2*)&Aout[((size_t)node << 7) + (((c0 >> 3) ^ swz) << 3) + (c0 & 7)] =
          make_uint2(lo, hi);
    }
  } else {
    if (node >= N) rr = (f32x4){0.f, 0.f, 0.f, 0.f};  // mask pad rows from pool
#pragma unroll
    for (int mask = 1; mask < 16; mask <<= 1)
#pragma unroll
      for (int c = 0; c < 4; c++) rr[c] += __shfl_xor(rr[c], mask);
    if (l15 == 0) {
#pragma unroll
      for (int c = 0; c < 4; c++) pbuf[(size_t)blockIdx.x * DH + c0 + c] = rr[c];
    }
  }
}

// ---------------- reduce per-block partials -> u ----------------
__global__ __launch_bounds__(256) void pool_reduce(const float* __restrict__ pbuf,
                                                   float* __restrict__ u, int nblk) {
  __shared__ float s[256];
  int tid = threadIdx.x;
  int c = tid & 127, h = tid >> 7;
  int chunk = (nblk + gridDim.x - 1) / gridDim.x;
  int r0 = blockIdx.x * chunk;
  int r1 = min(r0 + chunk, nblk);
  float sum = 0.f;
  for (int r = r0 + h; r < r1; r += 2) sum += pbuf[(size_t)r * 128 + c];
  s[tid] = sum;
  __syncthreads();
  if (tid < 128) atomicAdd(&u[c], s[tid] + s[tid + 128]);
}

// ---------------- final MLP on concat(u1/N + b2, u2/N + b2) ----------------
__global__ __launch_bounds__(256) void mlp_kernel(
    const float* __restrict__ u, const float* __restrict__ b2,
    const float* __restrict__ fc1w, const float* __restrict__ fc1b,
    const float* __restrict__ fc2w, const float* __restrict__ fc2b,
    float* __restrict__ out, int N) {
  __shared__ float uin[256];
  __shared__ float hred[128];
  int tid = threadIdx.x;
  uin[tid] = u[tid] * (1.f / (float)N) + b2[tid & 127];
  __syncthreads();
  if (tid < 128) {
    float s = fc1b[tid];
    for (int i = 0; i < 256; i++) s = fmaf(uin[i], fc1w[i * 128 + tid], s);
    s = fmaxf(s, 0.f);
    hred[tid] = s * fc2w[tid];
  }
  __syncthreads();
  if (tid == 0) {
    float s = fc2b[0];
    for (int i = 0; i < 128; i++) s += hred[i];
    out[0] = s;
  }
}

extern "C" void kernel_launch(void* const* d_in, const int* in_sizes, int n_in,
                              void* d_out, int out_size, void* d_ws, size_t ws_size,
                              hipStream_t stream) {
  const float* x[2] = {(const float*)d_in[0], (const float*)d_in[3]};
  const int* ei[2] = {(const int*)d_in[1], (const int*)d_in[4]};
  const int* et[2] = {(const int*)d_in[2], (const int*)d_in[5]};
  const float* Wp[3] = {(const float*)d_in[6], (const float*)d_in[9], (const float*)d_in[12]};
  const float* rootp[3] = {(const float*)d_in[7], (const float*)d_in[10], (const float*)d_in[13]};
  const float* biasp[3] = {(const float*)d_in[8], (const float*)d_in[11], (const float*)d_in[14]};
  const float* fc1w = (const float*)d_in[15];
  const float* fc1b = (const float*)d_in[16];
  const float* fc2w = (const float*)d_in[17];
  const float* fc2b = (const float*)d_in[18];

  const int N = in_sizes[0] / DH;  // meta packing requires N <= 65536
  const int E = in_sizes[2];
  const int Npad = (N + 127) & ~127;
  const int nt2 = (N + 15) / 16;    // rgcn_layer blocks (16 dsts each)
  const int M = N * R_ET;           // (dst, r) segments
  const int MB = (M + 1023) / 1024;

  char* ws = (char*)d_ws;
  size_t ob = 0;
  auto alloc = [&](size_t bytes) {
    void* p = ws + ob;
    ob = (ob + bytes + 255) & ~(size_t)255;
    return p;
  };
  int* cnt2 = (int*)alloc((size_t)M * 4);
  int* off2 = (int*)alloc((size_t)(M + 1) * 4);
  int* cursor2 = (int*)alloc((size_t)M * 4);
  int* bsum = (int*)alloc(1024 * 4);
  int2* meta = (int2*)alloc((size_t)E * 8);
  float* u = (float*)alloc(1024);
  float* pbuf = (float*)alloc((size_t)nt2 * DH * 4);
  ushort* A0 = (ushort*)alloc((size_t)Npad * DH * 2);
  ushort* A1 = (ushort*)alloc((size_t)Npad * DH * 2);
  ushort* Wt = (ushort*)alloc((size_t)3 * DH * KST * 2);
  (void)ws_size;

  hipMemsetAsync(u, 0, 2 * DH * sizeof(float), stream);
  for (int l = 0; l < 3; l++)
    wconv_kernel<<<9, 256, 0, stream>>>(rootp[l], Wp[l], Wt + (size_t)l * DH * KST);

  dim3 egrid((E + 255) / 256);
  const int total = N * DH, padtotal = Npad * DH;
  dim3 agrid((padtotal / 4 + 255) / 256);

  for (int g = 0; g < 2; g++) {
    hipMemsetAsync(cnt2, 0, (size_t)M * sizeof(int), stream);
    count_kernel<<<egrid, 256, 0, stream>>>(ei[g], et[g], cnt2, E);
    scanA<<<MB, 1024, 0, stream>>>(cnt2, off2, bsum, M);
    scanB<<<1, 1024, 0, stream>>>(bsum, MB);
    scanC<<<MB, 1024, 0, stream>>>(off2, cursor2, bsum, M, E);
    place_kernel<<<egrid, 256, 0, stream>>>(ei[g], et[g], cnt2, cursor2, meta, E);
    aconv_kernel<<<agrid, 256, 0, stream>>>(x[g], A0, total, padtotal);

    rgcn_layer<<<nt2, 512, 0, stream>>>(A0, off2, meta, Wt, biasp[0], A1, nullptr, N, 0);
    rgcn_layer<<<nt2, 512, 0, stream>>>(A1, off2, meta, Wt + (size_t)DH * KST,
                                        biasp[1], A0, nullptr, N, 0);
    rgcn_layer<<<nt2, 512, 0, stream>>>(A0, off2, meta, Wt + (size_t)2 * DH * KST,
                                        biasp[2], nullptr, pbuf, N, 1);
    pool_reduce<<<100, 256, 0, stream>>>(pbuf, u + g * DH, nt2);
  }
  mlp_kernel<<<1, 256, 0, stream>>>(u, biasp[2], fc1w, fc1b, fc2w, fc2b,
                                    (float*)d_out, N);
}

// Round 8
// 892.379 us; speedup vs baseline: 4.2611x; 4.2611x over previous
//
#include <hip/hip_runtime.h>

#define R_ET 8
#define DH 128
#define KST 1152  // stacked K: 8 relation blocks (1024) + root block (128)
#define GW 1024   // G row width (8 relation blocks only; root read from Ain)

typedef __bf16 bf16x8 __attribute__((ext_vector_type(8)));
typedef float f32x4 __attribute__((ext_vector_type(4)));

__device__ __forceinline__ ushort f2bf(float f) {
  unsigned u = __float_as_uint(f);
  u += 0x7fff + ((u >> 16) & 1);  // round-to-nearest-even
  return (ushort)(u >> 16);
}

// Swizzled layouts (row r, stacked-k): pos = ((k>>3) ^ (r&7))*8 + (k&7). The XOR
// touches only the low 3 bits of the 16B-block index, so every 128-wide chunk
// (16 blocks) is self-contained -> chunked GEMM staging works on raw bytes.
//
// Session lessons: r3 global-atomic contention scales with RMWs/line; r5/r7 LDS
// fp32 atomicAdd compiles to a CAS loop (no unsafe-fp-atomics) -> ~900cy/edge
// serialization; r5 391-block fusion = TLP collapse. This version: NO fp atomics,
// register-only aggregation at the proven 1-wave-per-dst gather geometry, plus
// one dense K=1152 MFMA GEMM in the proven r0 tile structure.

// ---------------- degree count per (dst, etype) segment ----------------
__global__ void count_kernel(const int* __restrict__ ei, const int* __restrict__ et,
                             int* __restrict__ cnt, int E) {
  int e = blockIdx.x * blockDim.x + threadIdx.x;
  if (e < E) atomicAdd(&cnt[ei[E + e] * R_ET + et[e]], 1);
}

// ---------------- 3-phase exclusive scan over M = N*R segment counts ----------------
__global__ __launch_bounds__(1024) void scanA(const int* __restrict__ cnt,
                                              int* __restrict__ off,
                                              int* __restrict__ bsum, int M) {
  __shared__ int s[1024];
  int tid = threadIdx.x;
  int i = blockIdx.x * 1024 + tid;
  int d = (i < M) ? cnt[i] : 0;
  s[tid] = d;
  __syncthreads();
  for (int st = 1; st < 1024; st <<= 1) {
    int v = (tid >= st) ? s[tid - st] : 0;
    __syncthreads();
    s[tid] += v;
    __syncthreads();
  }
  if (i < M) off[i] = s[tid] - d;
  if (tid == 1023) bsum[blockIdx.x] = s[1023];
}

__global__ __launch_bounds__(1024) void scanB(int* __restrict__ bsum, int nb) {
  __shared__ int s[1024];
  int tid = threadIdx.x;
  int v = (tid < nb) ? bsum[tid] : 0;
  s[tid] = v;
  __syncthreads();
  for (int st = 1; st < 1024; st <<= 1) {
    int x = (tid >= st) ? s[tid - st] : 0;
    __syncthreads();
    s[tid] += x;
    __syncthreads();
  }
  if (tid < nb) bsum[tid] = s[tid] - v;
}

__global__ __launch_bounds__(1024) void scanC(int* __restrict__ off,
                                              int* __restrict__ cursor,
                                              const int* __restrict__ bsum,
                                              int M, int E) {
  int i = blockIdx.x * 1024 + threadIdx.x;
  if (i < M) {
    int o = off[i] + bsum[blockIdx.x];
    off[i] = o;
    cursor[i] = o;
  }
  if (i == 0) off[M] = E;
}

// ---------------- place edges into (dst, r)-sorted slots ----------------
// meta: x = src (plain), y = 1/cnt(dst,r). Proven contention profile (~32/line).
__global__ void place_kernel(const int* __restrict__ ei, const int* __restrict__ et,
                             const int* __restrict__ cnt, int* __restrict__ cursor,
                             int2* __restrict__ meta, int E) {
  int e = blockIdx.x * blockDim.x + threadIdx.x;
  if (e >= E) return;
  int src = ei[e], dst = ei[E + e], r = et[e];
  int seg = dst * R_ET + r;
  int slot = atomicAdd(&cursor[seg], 1);
  meta[slot] = make_int2(src, __float_as_int(1.f / (float)cnt[seg]));
}

// ------- stacked weight convert: Wt[n][k], k = r*128+kin (r<8) or 1024+kin (root) ----
__global__ __launch_bounds__(256) void wconv_kernel(const float* __restrict__ root,
                                                    const float* __restrict__ W,
                                                    ushort* __restrict__ Wt) {
  int mat = blockIdx.x;  // 0..7 = W[r], 8 = root
  const float* src = (mat == 8) ? root : (W + (size_t)mat * DH * DH);
  for (int idx = threadIdx.x; idx < DH * DH; idx += 256) {
    int n = idx >> 7, kin = idx & 127;
    int k = mat * DH + kin;
    Wt[(size_t)n * KST + (((k >> 3) ^ (n & 7)) << 3) + (k & 7)] = f2bf(src[kin * DH + n]);
  }
}

// ---------------- activation convert (layer 0), zero-pads rows, swizzled ----------------
__global__ __launch_bounds__(256) void aconv_kernel(const float* __restrict__ src,
                                                    ushort* __restrict__ dst,
                                                    int total, int padtotal) {
  int i4 = (blockIdx.x * 256 + threadIdx.x) * 4;
  if (i4 >= padtotal) return;
  int row = i4 >> 7, k = i4 & 127;
  ushort4 o = make_ushort4(0, 0, 0, 0);
  if (i4 < total) {
    float4 v = *(const float4*)&src[i4];
    o = make_ushort4(f2bf(v.x), f2bf(v.y), f2bf(v.z), f2bf(v.w));
  }
  *(ushort4*)&dst[(size_t)row * DH + (((k >> 3) ^ (row & 7)) << 3) + (k & 7)] = o;
}

// ============ aggregation: 1 wave per dst (proven gather geometry) ==================
// Wave walks its dst's contiguous (dst,r)-sorted edge run once (64-edge chunks of
// meta in registers); 8 statically-unrolled relation accumulators (2 fp32/lane,
// lane = feats 2l, 2l+1); src rows read from L3-resident Ain (dword/lane).
// Flush: bf16 pair per relation into G[dst][r*128 + feat] (swizzled, 256B/seg,
// dst-major -> sequential). Empty segments naturally write zeros. Pad dsts
// [N, Npad) write zero rows (edge walk skipped).
__global__ __launch_bounds__(256) void agg_kernel(
    const int* __restrict__ off2, const int2* __restrict__ meta,
    const ushort* __restrict__ Ain, ushort* __restrict__ G, int N, int Npad) {
  int dst = blockIdx.x * 4 + (threadIdx.x >> 6);
  if (dst >= Npad) return;
  int lane = threadIdx.x & 63;
  const int kb = lane >> 2;             // (k>>3) for k = 2*lane
  const int klo = (lane * 2) & 7;       // (k&7)
  const int swz = dst & 7;

  int offv = 0;
  if (dst < N && lane < 9) offv = off2[dst * R_ET + lane];
  const int s_all = __shfl(offv, 0);
  const int e_end = __shfl(offv, 8);

  float ax[R_ET], ay[R_ET];
#pragma unroll
  for (int r = 0; r < R_ET; r++) { ax[r] = 0.f; ay[r] = 0.f; }

  for (int base = s_all; base < e_end; base += 64) {
    int m = min(64, e_end - base);
    int2 md = make_int2(0, 0);
    if (lane < m) md = meta[base + lane];
#pragma unroll
    for (int r = 0; r < R_ET; r++) {
      int s0 = max(__shfl(offv, r), base);
      int s1 = min(__shfl(offv, r + 1), base + m);
      for (int e = s0; e < s1; e++) {
        int p = __shfl(md.x, e - base);
        float c = __int_as_float(__shfl(md.y, e - base));
        unsigned v = *(const unsigned*)&Ain[((size_t)p << 7) + ((kb ^ (p & 7)) << 3) + klo];
        ax[r] = fmaf(__uint_as_float(v << 16), c, ax[r]);
        ay[r] = fmaf(__uint_as_float(v & 0xffff0000u), c, ay[r]);
      }
    }
  }

  ushort* Grow = G + (size_t)dst * GW;
#pragma unroll
  for (int r = 0; r < R_ET; r++) {
    unsigned o = (unsigned)f2bf(ax[r]) | ((unsigned)f2bf(ay[r]) << 16);
    *(unsigned*)&Grow[(((r * 16 + kb) ^ swz) << 3) + klo] = o;
  }
}

// ============ dense K=1152 MFMA GEMM: out = [G | Ain] x Wt (r0-proven tile) =========
// grid Npad/128; 256 thr (4 waves, 64x64 quadrants). 9 single-buffered 128-wide
// K-chunks staged via global_load_lds (A chunk<8 from G, chunk 8 = root from Ain;
// B from Wt). mfma(bfr, af) swapped operands -> lane l15 = node row, quad*4+reg =
// col. Epilogue: mid = bias+relu+swizzled bf16 (pad rows zeroed); last = column
// partials for mean pool (no bias -> pad rows contribute exact zeros).
__global__ __launch_bounds__(256) void gemm2(
    const ushort* __restrict__ G, const ushort* __restrict__ Ain,
    const ushort* __restrict__ Wt, const float* __restrict__ bias,
    ushort* __restrict__ Aout, float* __restrict__ pbuf, int N, int last) {
  __shared__ ushort As[128 * DH];  // 32 KB: A chunk (128 nodes x 128 k)
  __shared__ ushort Bs[128 * DH];  // 32 KB: B chunk (128 cols x 128 k)
  __shared__ float sb[2][DH];
  const int tid = threadIdx.x;
  const int wave = tid >> 6, lane = tid & 63;
  const int quad = lane >> 4, l15 = lane & 15;
  const int rbase = blockIdx.x * 128;
  const int wr = (wave >> 1) * 64, wc = (wave & 1) * 64;

  f32x4 acc[4][4];
#pragma unroll
  for (int i = 0; i < 4; i++)
#pragma unroll
    for (int j = 0; j < 4; j++) acc[i][j] = (f32x4){0.f, 0.f, 0.f, 0.f};

  for (int kc = 0; kc < 9; kc++) {
    if (kc) __syncthreads();  // prior chunk's reads done before overwrite
#pragma unroll
    for (int it = 0; it < 4; it++) {
      // unit i covers (row = i>>4, 16B-block b = i&15) of the 128x256B chunk
      int i = it * 256 + tid;
      int row = i >> 4, b = i & 15;
      const ushort* srcA = (kc < 8)
          ? G + (size_t)(rbase + row) * GW + kc * 128 + b * 8
          : Ain + (size_t)(rbase + row) * DH + b * 8;
      const ushort* srcB = Wt + (size_t)row * KST + kc * 128 + b * 8;
      __builtin_amdgcn_global_load_lds(
          (const __attribute__((address_space(1))) void*)srcA,
          (__attribute__((address_space(3))) void*)(As + (it * 256 + wave * 64) * 8),
          16, 0, 0);
      __builtin_amdgcn_global_load_lds(
          (const __attribute__((address_space(1))) void*)srcB,
          (__attribute__((address_space(3))) void*)(Bs + (it * 256 + wave * 64) * 8),
          16, 0, 0);
      i += 1024;  // second half
      row = i >> 4; b = i & 15;
      srcA = (kc < 8) ? G + (size_t)(rbase + row) * GW + kc * 128 + b * 8
                      : Ain + (size_t)(rbase + row) * DH + b * 8;
      srcB = Wt + (size_t)row * KST + kc * 128 + b * 8;
      __builtin_amdgcn_global_load_lds(
          (const __attribute__((address_space(1))) void*)srcA,
          (__attribute__((address_space(3))) void*)(As + ((it + 4) * 256 + wave * 64) * 8),
          16, 0, 0);
      __builtin_amdgcn_global_load_lds(
          (const __attribute__((address_space(1))) void*)srcB,
          (__attribute__((address_space(3))) void*)(Bs + ((it + 4) * 256 + wave * 64) * 8),
          16, 0, 0);
    }
    __syncthreads();

#pragma unroll
    for (int ks = 0; ks < 4; ks++) {
      bf16x8 af[4], bfr[4];
#pragma unroll
      for (int i = 0; i < 4; i++) {
        int ra = wr + i * 16 + l15;
        int rb = wc + i * 16 + l15;
        af[i] = *(const bf16x8*)&As[ra * DH + (((ks * 4 + quad) ^ (ra & 7)) << 3)];
        bfr[i] = *(const bf16x8*)&Bs[rb * DH + (((ks * 4 + quad) ^ (rb & 7)) << 3)];
      }
#pragma unroll
      for (int i = 0; i < 4; i++)
#pragma unroll
        for (int j = 0; j < 4; j++)
          acc[i][j] = __builtin_amdgcn_mfma_f32_16x16x32_bf16(bfr[j], af[i], acc[i][j], 0, 0, 0);
    }
  }

  // ---- epilogue ----
  if (!last) {
#pragma unroll
    for (int i = 0; i < 4; i++) {
      int node = rbase + wr + i * 16 + l15;
      bool ok = node < N;
#pragma unroll
      for (int j = 0; j < 4; j++) {
        int c0 = wc + j * 16 + quad * 4;
        float4 bv = *(const float4*)&bias[c0];
        unsigned lo = 0, hi = 0;
        if (ok) {
          lo = (unsigned)f2bf(fmaxf(acc[i][j][0] + bv.x, 0.f)) |
               ((unsigned)f2bf(fmaxf(acc[i][j][1] + bv.y, 0.f)) << 16);
          hi = (unsigned)f2bf(fmaxf(acc[i][j][2] + bv.z, 0.f)) |
               ((unsigned)f2bf(fmaxf(acc[i][j][3] + bv.w, 0.f)) << 16);
        }
        // pad rows written as zeros so next layer's staging reads zeros
        *(uint2*)&Aout[(size_t)node * DH + (((c0 >> 3) ^ (node & 7)) << 3) + (c0 & 7)] =
            make_uint2(lo, hi);
      }
    }
  } else {
    // column partials; pad rows are exact zeros (no bias here), so no masking
    if (tid < 2 * DH) ((float*)sb)[tid] = 0.f;
    __syncthreads();
    const int half = wave >> 1;  // waves {0,1} vs {2,3} cover disjoint col sets per half
#pragma unroll
    for (int j = 0; j < 4; j++) {
      f32x4 s;
#pragma unroll
      for (int c = 0; c < 4; c++)
        s[c] = acc[0][j][c] + acc[1][j][c] + acc[2][j][c] + acc[3][j][c];
#pragma unroll
      for (int mask = 1; mask < 16; mask <<= 1)
#pragma unroll
        for (int c = 0; c < 4; c++) s[c] += __shfl_xor(s[c], mask);
      if (l15 == 0) {
        int c0 = wc + j * 16 + quad * 4;
#pragma unroll
        for (int c = 0; c < 4; c++) sb[half][c0 + c] = s[c];  // unique writer per slot
      }
    }
    __syncthreads();
    if (tid < DH) pbuf[(size_t)blockIdx.x * DH + tid] = sb[0][tid] + sb[1][tid];
  }
}

// ---------------- reduce per-block partials -> u ----------------
__global__ __launch_bounds__(256) void pool_reduce(const float* __restrict__ pbuf,
                                                   float* __restrict__ u, int nblk) {
  __shared__ float s[256];
  int tid = threadIdx.x;
  int c = tid & 127, h = tid >> 7;
  int chunk = (nblk + gridDim.x - 1) / gridDim.x;
  int r0 = blockIdx.x * chunk;
  int r1 = min(r0 + chunk, nblk);
  float sum = 0.f;
  for (int r = r0 + h; r < r1; r += 2) sum += pbuf[(size_t)r * 128 + c];
  s[tid] = sum;
  __syncthreads();
  if (tid < 128) atomicAdd(&u[c], s[tid] + s[tid + 128]);
}

// ---------------- final MLP on concat(u1/N + b2, u2/N + b2) ----------------
__global__ __launch_bounds__(256) void mlp_kernel(
    const float* __restrict__ u, const float* __restrict__ b2,
    const float* __restrict__ fc1w, const float* __restrict__ fc1b,
    const float* __restrict__ fc2w, const float* __restrict__ fc2b,
    float* __restrict__ out, int N) {
  __shared__ float uin[256];
  __shared__ float hred[128];
  int tid = threadIdx.x;
  uin[tid] = u[tid] * (1.f / (float)N) + b2[tid & 127];
  __syncthreads();
  if (tid < 128) {
    float s = fc1b[tid];
    for (int i = 0; i < 256; i++) s = fmaf(uin[i], fc1w[i * 128 + tid], s);
    s = fmaxf(s, 0.f);
    hred[tid] = s * fc2w[tid];
  }
  __syncthreads();
  if (tid == 0) {
    float s = fc2b[0];
    for (int i = 0; i < 128; i++) s += hred[i];
    out[0] = s;
  }
}

extern "C" void kernel_launch(void* const* d_in, const int* in_sizes, int n_in,
                              void* d_out, int out_size, void* d_ws, size_t ws_size,
                              hipStream_t stream) {
  const float* x[2] = {(const float*)d_in[0], (const float*)d_in[3]};
  const int* ei[2] = {(const int*)d_in[1], (const int*)d_in[4]};
  const int* et[2] = {(const int*)d_in[2], (const int*)d_in[5]};
  const float* Wp[3] = {(const float*)d_in[6], (const float*)d_in[9], (const float*)d_in[12]};
  const float* rootp[3] = {(const float*)d_in[7], (const float*)d_in[10], (const float*)d_in[13]};
  const float* biasp[3] = {(const float*)d_in[8], (const float*)d_in[11], (const float*)d_in[14]};
  const float* fc1w = (const float*)d_in[15];
  const float* fc1b = (const float*)d_in[16];
  const float* fc2w = (const float*)d_in[17];
  const float* fc2b = (const float*)d_in[18];

  const int N = in_sizes[0] / DH;
  const int E = in_sizes[2];
  const int Npad = (N + 127) & ~127;
  const int ngB = Npad / 128;          // gemm2 blocks
  const int M = N * R_ET;              // (dst, r) segments
  const int MB = (M + 1023) / 1024;

  char* ws = (char*)d_ws;
  size_t ob = 0;
  auto alloc = [&](size_t bytes) {
    void* p = ws + ob;
    ob = (ob + bytes + 255) & ~(size_t)255;
    return p;
  };
  int* cnt2 = (int*)alloc((size_t)M * 4);
  int* off2 = (int*)alloc((size_t)(M + 1) * 4);
  int* cursor2 = (int*)alloc((size_t)M * 4);
  int* bsum = (int*)alloc(1024 * 4);
  int2* meta = (int2*)alloc((size_t)E * 8);
  float* u = (float*)alloc(1024);
  float* pbuf = (float*)alloc((size_t)ngB * DH * 4);
  ushort* A0 = (ushort*)alloc((size_t)Npad * DH * 2);
  ushort* A1 = (ushort*)alloc((size_t)Npad * DH * 2);
  ushort* G = (ushort*)alloc((size_t)Npad * GW * 2);
  ushort* Wt = (ushort*)alloc((size_t)3 * DH * KST * 2);
  (void)ws_size;

  hipMemsetAsync(u, 0, 2 * DH * sizeof(float), stream);
  for (int l = 0; l < 3; l++)
    wconv_kernel<<<9, 256, 0, stream>>>(rootp[l], Wp[l], Wt + (size_t)l * DH * KST);

  dim3 egrid((E + 255) / 256);
  dim3 nagrid((Npad + 3) / 4);
  const int total = N * DH, padtotal = Npad * DH;
  dim3 agrid((padtotal / 4 + 255) / 256);

  for (int g = 0; g < 2; g++) {
    hipMemsetAsync(cnt2, 0, (size_t)M * sizeof(int), stream);
    count_kernel<<<egrid, 256, 0, stream>>>(ei[g], et[g], cnt2, E);
    scanA<<<MB, 1024, 0, stream>>>(cnt2, off2, bsum, M);
    scanB<<<1, 1024, 0, stream>>>(bsum, MB);
    scanC<<<MB, 1024, 0, stream>>>(off2, cursor2, bsum, M, E);
    place_kernel<<<egrid, 256, 0, stream>>>(ei[g], et[g], cnt2, cursor2, meta, E);
    aconv_kernel<<<agrid, 256, 0, stream>>>(x[g], A0, total, padtotal);

    agg_kernel<<<nagrid, 256, 0, stream>>>(off2, meta, A0, G, N, Npad);
    gemm2<<<ngB, 256, 0, stream>>>(G, A0, Wt, biasp[0], A1, nullptr, N, 0);
    agg_kernel<<<nagrid, 256, 0, stream>>>(off2, meta, A1, G, N, Npad);
    gemm2<<<ngB, 256, 0, stream>>>(G, A1, Wt + (size_t)DH * KST, biasp[1], A0, nullptr, N, 0);
    agg_kernel<<<nagrid, 256, 0, stream>>>(off2, meta, A0, G, N, Npad);
    gemm2<<<ngB, 256, 0, stream>>>(G, A0, Wt + (size_t)2 * DH * KST, nullptr, nullptr, pbuf, N, 1);
    pool_reduce<<<100, 256, 0, stream>>>(pbuf, u + g * DH, ngB);
  }
  mlp_kernel<<<1, 256, 0, stream>>>(u, biasp[2], fc1w, fc1b, fc2w, fc2b,
                                    (float*)d_out, N);
}